// Round 17
// baseline (424.154 us; speedup 1.0000x reference)
//
#include <hip/hip_runtime.h>
#include <math.h>

// TriOut: z[L,L,Z] -> LN -> gated proj to C -> einsum('ilc,jlc->ijc') -> LN(C)
//         -> proj back to Z -> * sigmoid(zn@g_w+g_b)
// L=768, Z=128, C=32.  Output fp32 [L,L,Z].
//
// ws layout (disjoint):
//   a_t   : bf16 [C][L*L]   ( 37,748,736 B) @ 0          a, c-major
//   gate  : bf16 [L*L][Z]   (150,994,944 B) @ 37748736   sigmoid(zn@g_w+g_b)
//   obuf16: bf16 [C][L*L]   ( 37,748,736 B) @ 188743680  einsum result, c-major
//   wfrag : bf16 [12*4][64][8] (49,152 B)   @ 226492416  a/ag/g weights, frag order
//   ofrag : bf16 [8][64][8]    ( 8,192 B)   @ 226541568  o_w frag order (K=32)

#define LDIM 768
#define LL   (768 * 768)
#define ZD   128
#define CD   32

typedef __bf16 bf16x8 __attribute__((ext_vector_type(8)));
typedef float  f32x4  __attribute__((ext_vector_type(4)));

__device__ __forceinline__ ushort f2bf(float f) {
    __bf16 h = (__bf16)f;                      // RNE convert
    return __builtin_bit_cast(ushort, h);
}
__device__ __forceinline__ float bf2f(ushort u) {
    return __builtin_bit_cast(float, ((unsigned)u) << 16);
}
// fast sigmoid: v_exp_f32 + v_rcp_f32 (~1 ulp fp32 -- far below bf16 rounding)
__device__ __forceinline__ float sigm(float x) {
    return __builtin_amdgcn_rcpf(1.0f + __expf(-x));
}

// ---------------------------------------------------------------------------
// k0: pack weights into MFMA B-fragment order (frag f, lane l = fr + 16*hi):
//   wfrag[f=n*4+kk][l][j] = W[n*16+fr][kk*32+hi*8+j]   (W = [a_w;ag_w;g_w])
//   ofrag[n][l][j]        = o_w[n*16+fr][hi*8+j]        (K=32, single step)
// ---------------------------------------------------------------------------
__global__ __launch_bounds__(256) void k0_wfrag(
    const float* __restrict__ aw, const float* __restrict__ agw,
    const float* __restrict__ gw, const float* __restrict__ ow,
    ushort* __restrict__ wfrag, ushort* __restrict__ ofrag)
{
    const int idx = blockIdx.x * 256 + threadIdx.x;   // 3584 total
    if (idx >= 3584) return;
    union { ushort us[8]; uint4 q; } pk;
    if (idx < 3072) {
        const int f = idx, n4 = f >> 6, lane = f & 63;
        const int n = n4 >> 2, kk = n4 & 3;
        const int fr = lane & 15, hi = lane >> 4;
        const int ch = n * 16 + fr;
        const int k0 = kk * 32 + hi * 8;
        const float* src = (ch < 32) ? (aw + ch * ZD)
                         : (ch < 64) ? (agw + (ch - 32) * ZD)
                                     : (gw + (ch - 64) * ZD);
        #pragma unroll
        for (int j = 0; j < 8; ++j) pk.us[j] = f2bf(src[k0 + j]);
        *(uint4*)&wfrag[(size_t)f * 8] = pk.q;
    } else {
        const int e = idx - 3072;                     // 512 ofrag entries
        const int n = e >> 6, lane = e & 63;
        const int fr = lane & 15, hi = lane >> 4;
        const float* src = ow + (n * 16 + fr) * CD + hi * 8;
        #pragma unroll
        for (int j = 0; j < 8; ++j) pk.us[j] = f2bf(src[j]);
        *(uint4*)&ofrag[(size_t)e * 8] = pk.q;
    }
}

// ---------------------------------------------------------------------------
// k1 v8: same proven channel-split structure, 32-ROW CHUNKS for occupancy.
// 2304 blocks x 8 chunks of 32 rows; halving the chunk halves the two big
// VGPR consumers (zreg prefetch 32->16, acc 48->24) -> fits 4 waves/SIMD
// (launch_bounds (256,4)), 16 waves/CU vs 12.  LDS 17.4 KB.
//   wave w owns 3 n-tiles for ALL 32 rows (2 m-tiles):
//     w0:{0(a0),2(ag0),4(g0)}  w1:{1(a1),3(ag1),5(g1)}  w2:{6,7,8}  w3:{9,10,11}
//   LN: 8 lanes/row x 16 elems.  Pipelined gate copy-out (R13).
//   (direct scattered gate stores measured WORSE -- L2 request-rate, R10.)
// ---------------------------------------------------------------------------
__global__ __launch_bounds__(256, 4) void k1_ln_proj(
    const float* __restrict__ z, const float* __restrict__ nw, const float* __restrict__ nb,
    const ushort* __restrict__ wfrag,
    const float* __restrict__ ab, const float* __restrict__ agb, const float* __restrict__ gb,
    ushort* __restrict__ a_t, ushort* __restrict__ gate)
{
    __shared__ ushort zn[32][136];
    __shared__ ushort gl[32][136];

    const int tid = threadIdx.x;
    const int lane = tid & 63, wave = tid >> 6;
    const int fr = lane & 15, hi = lane >> 4;

    // owned n-tiles
    const int t0 = (wave < 2) ? wave     : 6 + (wave - 2) * 3;
    const int t1 = (wave < 2) ? wave + 2 : t0 + 1;
    const int t2 = (wave < 2) ? wave + 4 : t0 + 2;

    // B-fragments: loaded once, held in registers (12 x 4 VGPR)
    bf16x8 bv0[4], bv1[4], bv2[4];
    {
        const ushort* wl = wfrag + (size_t)lane * 8;
        #pragma unroll
        for (int kk = 0; kk < 4; ++kk) {
            bv0[kk] = *(const bf16x8*)(wl + (size_t)(t0 * 4 + kk) * 512);
            bv1[kk] = *(const bf16x8*)(wl + (size_t)(t1 * 4 + kk) * 512);
            bv2[kk] = *(const bf16x8*)(wl + (size_t)(t2 * 4 + kk) * 512);
        }
    }

    // biases (per-lane scalars, hoisted)
    float abv = 0.f, agbv = 0.f, gbv0 = 0.f, gbv1 = 0.f, gbv2;
    if (wave < 2) {
        abv  = ab[wave * 16 + fr];
        agbv = agb[wave * 16 + fr];
        gbv2 = gb[t2 * 16 - 64 + fr];
    } else {
        gbv0 = gb[t0 * 16 - 64 + fr];
        gbv1 = gb[t1 * 16 - 64 + fr];
        gbv2 = gb[t2 * 16 - 64 + fr];
    }

    const size_t blockrow = (size_t)blockIdx.x * 256;
    const int lr = tid >> 3, seg = tid & 7;     // LN: 8 threads/row, 16 elems

    float4 zreg[4];
    {
        const float4* zp = (const float4*)(z + (blockrow + lr) * ZD + seg * 16);
        #pragma unroll
        for (int q = 0; q < 4; ++q) zreg[q] = zp[q];
    }

    // coalesced gate copy-out of gl for chunk cc (32 rows = 512 uint4)
    auto copy_out = [&](int cc) {
        const size_t rbp = blockrow + (size_t)cc * 32;
        #pragma unroll
        for (int it = 0; it < 2; ++it) {
            const int idx = it * 256 + tid;
            const int r = idx >> 4, cq = idx & 15;
            *(uint4*)&gate[(rbp + r) * ZD + cq * 8] = *(const uint4*)&gl[r][cq * 8];
        }
    };

    for (int c = 0; c < 8; ++c) {
        __syncthreads();   // A: prev MFMA done (zn free), prev gl complete

        // ---- LN from prefetched regs -> zn bf16 ----
        {
            float v[16];
            #pragma unroll
            for (int q = 0; q < 4; ++q) {
                v[q * 4 + 0] = zreg[q].x; v[q * 4 + 1] = zreg[q].y;
                v[q * 4 + 2] = zreg[q].z; v[q * 4 + 3] = zreg[q].w;
            }
            float s = 0.f, ss = 0.f;
            #pragma unroll
            for (int e = 0; e < 16; ++e) { s += v[e]; ss += v[e] * v[e]; }
            s += __shfl_xor(s, 1); ss += __shfl_xor(ss, 1);
            s += __shfl_xor(s, 2); ss += __shfl_xor(ss, 2);
            s += __shfl_xor(s, 4); ss += __shfl_xor(ss, 4);
            const float mu  = s * (1.f / 128.f);
            const float var = ss * (1.f / 128.f) - mu * mu;
            const float rs  = rsqrtf(var + 1e-5f);
            union { ushort u[16]; uint4 q4[2]; } pk;
            #pragma unroll
            for (int e = 0; e < 16; ++e) {
                const int k = seg * 16 + e;
                pk.u[e] = f2bf((v[e] - mu) * rs * nw[k] + nb[k]);
            }
            *(uint4*)&zn[lr][seg * 16]     = pk.q4[0];
            *(uint4*)&zn[lr][seg * 16 + 8] = pk.q4[1];
        }

        // ---- pipelined gate copy-out of PREVIOUS chunk (gl stable here) ----
        if (c > 0) copy_out(c - 1);

        // ---- prefetch next chunk's z (regs are dead after the pack) ----
        if (c < 7) {
            const float4* zp = (const float4*)(z + (blockrow + (c + 1) * 32 + lr) * ZD + seg * 16);
            #pragma unroll
            for (int q = 0; q < 4; ++q) zreg[q] = zp[q];
        }
        __syncthreads();   // B: zn ready, copy-out reads of gl done

        // ---- MFMA: 2 m-tiles x 3 owned n-tiles x 4 k ----
        f32x4 acc0[2], acc1[2], acc2[2];
        #pragma unroll
        for (int m = 0; m < 2; ++m) {
            acc0[m] = (f32x4){0.f, 0.f, 0.f, 0.f};
            acc1[m] = (f32x4){0.f, 0.f, 0.f, 0.f};
            acc2[m] = (f32x4){0.f, 0.f, 0.f, 0.f};
        }
        #pragma unroll
        for (int m = 0; m < 2; ++m) {
            bf16x8 afm[4];
            #pragma unroll
            for (int kk = 0; kk < 4; ++kk)
                afm[kk] = *(const bf16x8*)&zn[m * 16 + fr][kk * 32 + hi * 8];
            #pragma unroll
            for (int kk = 0; kk < 4; ++kk) {
                acc0[m] = __builtin_amdgcn_mfma_f32_16x16x32_bf16(afm[kk], bv0[kk], acc0[m], 0, 0, 0);
                acc1[m] = __builtin_amdgcn_mfma_f32_16x16x32_bf16(afm[kk], bv1[kk], acc1[m], 0, 0, 0);
                acc2[m] = __builtin_amdgcn_mfma_f32_16x16x32_bf16(afm[kk], bv2[kk], acc2[m], 0, 0, 0);
            }
        }

        // ---- epilogue ----
        const size_t rb = blockrow + (size_t)c * 32;
        if (wave < 2) {
            // a = (a_lin + ab) * sigm(ag_lin + agb) -> a_t c-major
            const int ch = wave * 16 + fr;
            #pragma unroll
            for (int m = 0; m < 2; ++m) {
                union { ushort u[4]; uint2 d; } pk;
                #pragma unroll
                for (int q = 0; q < 4; ++q)
                    pk.u[q] = f2bf((acc0[m][q] + abv) * sigm(acc1[m][q] + agbv));
                *(uint2*)&a_t[(size_t)ch * LL + rb + m * 16 + hi * 4] = pk.d;
            }
            // gate tile t2 -> gl transpose
            const int gch = t2 * 16 - 64 + fr;
            #pragma unroll
            for (int m = 0; m < 2; ++m)
                #pragma unroll
                for (int q = 0; q < 4; ++q)
                    gl[m * 16 + hi * 4 + q][gch] = f2bf(sigm(acc2[m][q] + gbv2));
        } else {
            const int g0 = t0 * 16 - 64 + fr;
            const int g1 = t1 * 16 - 64 + fr;
            const int g2 = t2 * 16 - 64 + fr;
            #pragma unroll
            for (int m = 0; m < 2; ++m)
                #pragma unroll
                for (int q = 0; q < 4; ++q) {
                    const int row = m * 16 + hi * 4 + q;
                    gl[row][g0] = f2bf(sigm(acc0[m][q] + gbv0));
                    gl[row][g1] = f2bf(sigm(acc1[m][q] + gbv1));
                    gl[row][g2] = f2bf(sigm(acc2[m][q] + gbv2));
                }
        }
    }
    __syncthreads();       // chunk 7's gl complete
    copy_out(7);
}

// ---------------------------------------------------------------------------
// k2 v4 (R15/R16): 128x128 tile + bijective XCD swizzle (672 % 8 == 0).
// BK=32 double-buffered, global_load_lds, 4 waves 2x2, acc[4][4].
// ---------------------------------------------------------------------------
__global__ __launch_bounds__(256) void k2_einsum(
    const ushort* __restrict__ a_t, ushort* __restrict__ obuf16)
{
    __shared__ ushort As[2][128][32];
    __shared__ ushort Bs[2][128][32];

    const int tid = threadIdx.x;
    const int lid = blockIdx.y * 21 + blockIdx.x;     // dispatch-linear id
    const int swz = (lid & 7) * 84 + (lid >> 3);      // bijective XCD cluster
    const int c = swz / 21;
    int p = swz % 21, bi = 0;                         // 21 pairs over 6 tiles
    while (p >= 6 - bi) { p -= 6 - bi; ++bi; }
    const int bj = bi + p;
    const int i0 = bi * 128, j0 = bj * 128;
    const ushort* base = a_t + (size_t)c * LL;

    const int wave = tid >> 6, lane = tid & 63;
    const int wr = (wave >> 1) * 64, wc = (wave & 1) * 64;
    const int fr = lane & 15, hi = lane >> 4, k8 = hi * 8;

    f32x4 acc[4][4];
    #pragma unroll
    for (int m = 0; m < 4; ++m)
        #pragma unroll
        for (int n = 0; n < 4; ++n)
            acc[m][n] = (f32x4){0.f, 0.f, 0.f, 0.f};

    auto stage = [&](int b, int kc) {
        #pragma unroll
        for (int i = 0; i < 2; ++i) {
            const int idx = i * 256 + tid;       // 512 x 16B chunks
            const int row = idx >> 2, sc = (idx & 3) * 8;
            __builtin_amdgcn_global_load_lds(
                (const uint*)(base + (size_t)(i0 + row) * LDIM + kc * 32 + sc),
                (uint*)&As[b][row][sc], 16, 0, 0);
            __builtin_amdgcn_global_load_lds(
                (const uint*)(base + (size_t)(j0 + row) * LDIM + kc * 32 + sc),
                (uint*)&Bs[b][row][sc], 16, 0, 0);
        }
    };

    stage(0, 0);
    __syncthreads();
    for (int kc = 0; kc < 24; ++kc) {
        const int cur = kc & 1;
        if (kc + 1 < 24) stage(cur ^ 1, kc + 1);

        bf16x8 av[4], bv[4];
        #pragma unroll
        for (int m = 0; m < 4; ++m)
            av[m] = *(const bf16x8*)&As[cur][wr + m * 16 + fr][k8];
        #pragma unroll
        for (int n = 0; n < 4; ++n)
            bv[n] = *(const bf16x8*)&Bs[cur][wc + n * 16 + fr][k8];

        #pragma unroll
        for (int m = 0; m < 4; ++m)
            #pragma unroll
            for (int n = 0; n < 4; ++n)
                acc[m][n] = __builtin_amdgcn_mfma_f32_16x16x32_bf16(
                    av[m], bv[n], acc[m][n], 0, 0, 0);
        __syncthreads();
    }

    ushort* ob = obuf16 + (size_t)c * LL;
    #pragma unroll
    for (int m = 0; m < 4; ++m)
        #pragma unroll
        for (int n = 0; n < 4; ++n) {
            #pragma unroll
            for (int q = 0; q < 4; ++q) {
                const int row = i0 + wr + m * 16 + hi * 4 + q;
                const int col = j0 + wc + n * 16 + fr;
                ob[(size_t)row * LDIM + col] = f2bf(acc[m][n][q]);
            }
            if (bi != bj) {
                const int mrow = j0 + wc + n * 16 + fr;
                const int mcol = i0 + wr + m * 16 + hi * 4;
                union { ushort u[4]; uint2 d; } pk;
                #pragma unroll
                for (int q = 0; q < 4; ++q) pk.u[q] = f2bf(acc[m][n][q]);
                *(uint2*)&ob[(size_t)mrow * LDIM + mcol] = pk.d;
            }
        }
}

// ---------------------------------------------------------------------------
// k3 v7 (R16 measured-best): bf16 LDS, de-aliased, single cross-wave barrier.
//   LDS: Ol[64][40] + An[64][40] + Res[64][136], all ushort = 27.6 KB.
//   Everything after the gather-barrier is wave-private; lgkmcnt fences
//   guard same-wave LDS handoffs.  Big-stream patterns coalesced.
// ---------------------------------------------------------------------------
__global__ __launch_bounds__(256) void k3_out(
    const ushort* __restrict__ obuf16,
    const float* __restrict__ onw, const float* __restrict__ onb,
    const ushort* __restrict__ ofrag, const float* __restrict__ obias,
    const ushort* __restrict__ gate, float* __restrict__ out)
{
    __shared__ ushort Ol[64][40];
    __shared__ ushort An[64][40];
    __shared__ ushort Res[64][136];

    const int tid = threadIdx.x;
    const int lane = tid & 63, wave = tid >> 6;
    const int fr = lane & 15, hi = lane >> 4;
    const size_t rowbase = (size_t)blockIdx.x * 64;
    const int wrow = wave * 16;

    // ---- o_w frags: all 8 n-tiles in regs (coalesced 16B/lane, L2-hot) ----
    bf16x8 ofr[8];
    #pragma unroll
    for (int n = 0; n < 8; ++n)
        ofr[n] = *(const bf16x8*)&ofrag[(size_t)n * 512 + lane * 8];

    // ---- gather obuf16 (c-major bf16): wave handles 8 channels, 2 rows/uint ----
    #pragma unroll
    for (int cc = 0; cc < 4; ++cc) {
        const int ch = wave * 8 + cc * 2 + (lane >> 5);
        const int r2 = (lane & 31) * 2;
        const uint uu = *(const uint*)&obuf16[(size_t)ch * LL + rowbase + r2];
        Ol[r2][ch]     = (ushort)(uu & 0xffff);
        Ol[r2 + 1][ch] = (ushort)(uu >> 16);
    }
    __syncthreads();   // the ONLY cross-wave dependency

    // ---- LN over C=32 (wave-private rows): 4 lanes/row, 8 ch each ----
    {
        const int r = wrow + (lane >> 2), seg = lane & 3;
        union { uint4 q; ushort us[8]; } raw;
        raw.q = *(const uint4*)&Ol[r][seg * 8];
        float v[8];
        #pragma unroll
        for (int e = 0; e < 8; ++e) v[e] = bf2f(raw.us[e]);
        float s = 0.f, ss = 0.f;
        #pragma unroll
        for (int e = 0; e < 8; ++e) { s += v[e]; ss += v[e] * v[e]; }
        s += __shfl_xor(s, 1); ss += __shfl_xor(ss, 1);
        s += __shfl_xor(s, 2); ss += __shfl_xor(ss, 2);
        const float mu  = s * (1.f / 32.f);
        const float var = ss * (1.f / 32.f) - mu * mu;
        const float rs  = rsqrtf(var + 1e-5f);
        union { ushort us[8]; uint4 q; } pk;
        #pragma unroll
        for (int e = 0; e < 8; ++e) {
            const int c = seg * 8 + e;
            pk.us[e] = f2bf((v[e] - mu) * rs * onw[c] + onb[c]);
        }
        *(uint4*)&An[r][seg * 8] = pk.q;
    }
    asm volatile("s_waitcnt lgkmcnt(0)" ::: "memory");

    // ---- MFMA: wave w -> own rows wrow..+15, 128 outputs, single k-step ----
    const bf16x8 af = *(const bf16x8*)&An[wrow + fr][hi * 8];
    f32x4 acc[8];
    #pragma unroll
    for (int n = 0; n < 8; ++n)
        acc[n] = __builtin_amdgcn_mfma_f32_16x16x32_bf16(
            af, ofr[n], (f32x4){0.f, 0.f, 0.f, 0.f}, 0, 0, 0);

    // ---- +bias -> Res bf16 (own rows only) ----
    #pragma unroll
    for (int n = 0; n < 8; ++n) {
        const int ch = n * 16 + fr;
        const float obv = obias[ch];
        #pragma unroll
        for (int q = 0; q < 4; ++q)
            Res[wrow + hi * 4 + q][ch] = f2bf(acc[n][q] + obv);
    }
    asm volatile("s_waitcnt lgkmcnt(0)" ::: "memory");

    // ---- Res * gate -> out (wave-private rows, coalesced big streams) ----
    #pragma unroll
    for (int it = 0; it < 8; ++it) {
        const int r = wrow + it * 2 + (lane >> 5);     // 2 rows/iter
        const int ch = (lane & 31) * 4;
        union { uint2 d; ushort us[4]; } rv, g;
        rv.d = *(const uint2*)&Res[r][ch];
        g.d  = *(const uint2*)&gate[(rowbase + r) * ZD + ch];
        float4 w;
        w.x = bf2f(rv.us[0]) * bf2f(g.us[0]);
        w.y = bf2f(rv.us[1]) * bf2f(g.us[1]);
        w.z = bf2f(rv.us[2]) * bf2f(g.us[2]);
        w.w = bf2f(rv.us[3]) * bf2f(g.us[3]);
        *(float4*)&out[(rowbase + r) * ZD + ch] = w;
    }
}

extern "C" void kernel_launch(void* const* d_in, const int* in_sizes, int n_in,
                              void* d_out, int out_size, void* d_ws, size_t ws_size,
                              hipStream_t stream) {
    (void)in_sizes; (void)n_in; (void)out_size; (void)ws_size;
    const float* z   = (const float*)d_in[0];
    const float* nw  = (const float*)d_in[1];
    const float* nb  = (const float*)d_in[2];
    const float* onw = (const float*)d_in[3];
    const float* onb = (const float*)d_in[4];
    const float* aw  = (const float*)d_in[5];
    const float* ab  = (const float*)d_in[6];
    const float* agw = (const float*)d_in[7];
    const float* agb = (const float*)d_in[8];
    const float* gw  = (const float*)d_in[9];
    const float* gb  = (const float*)d_in[10];
    const float* ow  = (const float*)d_in[11];
    const float* ob  = (const float*)d_in[12];

    char* ws = (char*)d_ws;
    ushort* a_t    = (ushort*)ws;                       // 37,748,736 B
    ushort* gate   = (ushort*)(ws + 37748736);          // 150,994,944 B
    ushort* obuf16 = (ushort*)(ws + 188743680);         // 37,748,736 B
    ushort* wfrag  = (ushort*)(ws + 226492416);         // 49,152 B
    ushort* ofrag  = (ushort*)(ws + 226541568);         // 8,192 B

    k0_wfrag<<<14, 256, 0, stream>>>(aw, agw, gw, ow, wfrag, ofrag);
    k1_ln_proj<<<LL / 256, 256, 0, stream>>>(z, nw, nb, wfrag, ab, agb, gb,
                                             a_t, gate);
    k2_einsum<<<dim3(21, 32), 256, 0, stream>>>(a_t, obuf16);
    k3_out<<<LL / 64, 256, 0, stream>>>(obuf16, onw, onb, ofrag, ob, gate,
                                        (float*)d_out);
}

// Round 18
// 255.524 us; speedup vs baseline: 1.6599x; 1.6599x over previous
//
#include <hip/hip_runtime.h>
#include <math.h>

// TriOut: z[L,L,Z] -> LN -> gated proj to C -> einsum('ilc,jlc->ijc') -> LN(C)
//         -> proj back to Z -> * sigmoid(zn@g_w+g_b)
// L=768, Z=128, C=32.  Output fp32 [L,L,Z].
//
// R18 = exact revert to R16 measured-best (255.87 us):
//   k1 v7: 64-row chunks, channel-split, pipelined gate copy-out.
//          (32-row chunks measured FETCH x5 / WRITE x2 -- L3-reuse thrash, R17)
//   k2 v4: 128^2 symmetric-triangular + XCD swizzle + global_load_lds.
//   k3 v7: bf16 LDS, de-aliased, single cross-wave barrier.
//
// ws layout (disjoint):
//   a_t   : bf16 [C][L*L]   ( 37,748,736 B) @ 0          a, c-major
//   gate  : bf16 [L*L][Z]   (150,994,944 B) @ 37748736   sigmoid(zn@g_w+g_b)
//   obuf16: bf16 [C][L*L]   ( 37,748,736 B) @ 188743680  einsum result, c-major
//   wfrag : bf16 [12*4][64][8] (49,152 B)   @ 226492416  a/ag/g weights, frag order
//   ofrag : bf16 [8][64][8]    ( 8,192 B)   @ 226541568  o_w frag order (K=32)

#define LDIM 768
#define LL   (768 * 768)
#define ZD   128
#define CD   32

typedef __bf16 bf16x8 __attribute__((ext_vector_type(8)));
typedef float  f32x4  __attribute__((ext_vector_type(4)));

__device__ __forceinline__ ushort f2bf(float f) {
    __bf16 h = (__bf16)f;                      // RNE convert
    return __builtin_bit_cast(ushort, h);
}
__device__ __forceinline__ float bf2f(ushort u) {
    return __builtin_bit_cast(float, ((unsigned)u) << 16);
}
// fast sigmoid: v_exp_f32 + v_rcp_f32 (~1 ulp fp32 -- far below bf16 rounding)
__device__ __forceinline__ float sigm(float x) {
    return __builtin_amdgcn_rcpf(1.0f + __expf(-x));
}

// ---------------------------------------------------------------------------
// k0: pack weights into MFMA B-fragment order (frag f, lane l = fr + 16*hi):
//   wfrag[f=n*4+kk][l][j] = W[n*16+fr][kk*32+hi*8+j]   (W = [a_w;ag_w;g_w])
//   ofrag[n][l][j]        = o_w[n*16+fr][hi*8+j]        (K=32, single step)
// ---------------------------------------------------------------------------
__global__ __launch_bounds__(256) void k0_wfrag(
    const float* __restrict__ aw, const float* __restrict__ agw,
    const float* __restrict__ gw, const float* __restrict__ ow,
    ushort* __restrict__ wfrag, ushort* __restrict__ ofrag)
{
    const int idx = blockIdx.x * 256 + threadIdx.x;   // 3584 total
    if (idx >= 3584) return;
    union { ushort us[8]; uint4 q; } pk;
    if (idx < 3072) {
        const int f = idx, n4 = f >> 6, lane = f & 63;
        const int n = n4 >> 2, kk = n4 & 3;
        const int fr = lane & 15, hi = lane >> 4;
        const int ch = n * 16 + fr;
        const int k0 = kk * 32 + hi * 8;
        const float* src = (ch < 32) ? (aw + ch * ZD)
                         : (ch < 64) ? (agw + (ch - 32) * ZD)
                                     : (gw + (ch - 64) * ZD);
        #pragma unroll
        for (int j = 0; j < 8; ++j) pk.us[j] = f2bf(src[k0 + j]);
        *(uint4*)&wfrag[(size_t)f * 8] = pk.q;
    } else {
        const int e = idx - 3072;                     // 512 ofrag entries
        const int n = e >> 6, lane = e & 63;
        const int fr = lane & 15, hi = lane >> 4;
        const float* src = ow + (n * 16 + fr) * CD + hi * 8;
        #pragma unroll
        for (int j = 0; j < 8; ++j) pk.us[j] = f2bf(src[j]);
        *(uint4*)&ofrag[(size_t)e * 8] = pk.q;
    }
}

// ---------------------------------------------------------------------------
// k1 v7 (R13/R14/R16 measured-best): channel-split, pipelined gate copy-out.
// 2304 blocks x 4 chunks of 64 rows; 2 barriers/chunk + 1 final.
//   wave w owns 3 n-tiles for ALL 64 rows:
//     w0:{0(a0),2(ag0),4(g0)}  w1:{1(a1),3(ag1),5(g1)}  w2:{6,7,8}  w3:{9,10,11}
//   (direct scattered gate stores: WORSE, L2 request-rate, R10.
//    32-row chunks: WORSE, FETCH x5 L3-thrash, R17.)
// ---------------------------------------------------------------------------
__global__ __launch_bounds__(256) void k1_ln_proj(
    const float* __restrict__ z, const float* __restrict__ nw, const float* __restrict__ nb,
    const ushort* __restrict__ wfrag,
    const float* __restrict__ ab, const float* __restrict__ agb, const float* __restrict__ gb,
    ushort* __restrict__ a_t, ushort* __restrict__ gate)
{
    __shared__ ushort zn[64][136];
    __shared__ ushort gl[64][136];

    const int tid = threadIdx.x;
    const int lane = tid & 63, wave = tid >> 6;
    const int fr = lane & 15, hi = lane >> 4;

    // owned n-tiles
    const int t0 = (wave < 2) ? wave     : 6 + (wave - 2) * 3;
    const int t1 = (wave < 2) ? wave + 2 : t0 + 1;
    const int t2 = (wave < 2) ? wave + 4 : t0 + 2;

    // B-fragments: loaded once, held in registers (12 x 4 VGPR)
    bf16x8 bv0[4], bv1[4], bv2[4];
    {
        const ushort* wl = wfrag + (size_t)lane * 8;
        #pragma unroll
        for (int kk = 0; kk < 4; ++kk) {
            bv0[kk] = *(const bf16x8*)(wl + (size_t)(t0 * 4 + kk) * 512);
            bv1[kk] = *(const bf16x8*)(wl + (size_t)(t1 * 4 + kk) * 512);
            bv2[kk] = *(const bf16x8*)(wl + (size_t)(t2 * 4 + kk) * 512);
        }
    }

    // biases (per-lane scalars, hoisted)
    float abv = 0.f, agbv = 0.f, gbv0 = 0.f, gbv1 = 0.f, gbv2;
    if (wave < 2) {
        abv  = ab[wave * 16 + fr];
        agbv = agb[wave * 16 + fr];
        gbv2 = gb[t2 * 16 - 64 + fr];
    } else {
        gbv0 = gb[t0 * 16 - 64 + fr];
        gbv1 = gb[t1 * 16 - 64 + fr];
        gbv2 = gb[t2 * 16 - 64 + fr];
    }

    const size_t blockrow = (size_t)blockIdx.x * 256;
    const int lr = tid >> 2, seg = tid & 3;     // LN: 4 threads/row

    float4 zreg[8];
    {
        const float4* zp = (const float4*)(z + (blockrow + lr) * ZD + seg * 32);
        #pragma unroll
        for (int q = 0; q < 8; ++q) zreg[q] = zp[q];
    }

    // coalesced gate copy-out of gl for chunk cc
    auto copy_out = [&](int cc) {
        const size_t rbp = blockrow + (size_t)cc * 64;
        #pragma unroll
        for (int it = 0; it < 4; ++it) {
            const int idx = it * 256 + tid;    // 1024 uint4 chunks
            const int r = idx >> 4, cq = idx & 15;
            *(uint4*)&gate[(rbp + r) * ZD + cq * 8] = *(const uint4*)&gl[r][cq * 8];
        }
    };

    for (int c = 0; c < 4; ++c) {
        __syncthreads();   // A: prev MFMA done (zn free), prev gl complete

        // ---- LN from prefetched regs -> zn bf16 ----
        {
            float v[32];
            #pragma unroll
            for (int q = 0; q < 8; ++q) {
                v[q * 4 + 0] = zreg[q].x; v[q * 4 + 1] = zreg[q].y;
                v[q * 4 + 2] = zreg[q].z; v[q * 4 + 3] = zreg[q].w;
            }
            float s = 0.f, ss = 0.f;
            #pragma unroll
            for (int e = 0; e < 32; ++e) { s += v[e]; ss += v[e] * v[e]; }
            s += __shfl_xor(s, 1); ss += __shfl_xor(ss, 1);
            s += __shfl_xor(s, 2); ss += __shfl_xor(ss, 2);
            const float mu  = s * (1.f / 128.f);
            const float var = ss * (1.f / 128.f) - mu * mu;
            const float rs  = rsqrtf(var + 1e-5f);
            union { ushort u[32]; uint4 q4[4]; } pk;
            #pragma unroll
            for (int e = 0; e < 32; ++e) {
                const int k = seg * 32 + e;
                pk.u[e] = f2bf((v[e] - mu) * rs * nw[k] + nb[k]);
            }
            #pragma unroll
            for (int q = 0; q < 4; ++q)
                *(uint4*)&zn[lr][seg * 32 + q * 8] = pk.q4[q];
        }

        // ---- pipelined gate copy-out of PREVIOUS chunk (gl stable here) ----
        if (c > 0) copy_out(c - 1);

        // ---- prefetch next chunk's z (regs are dead after the pack) ----
        if (c < 3) {
            const float4* zp = (const float4*)(z + (blockrow + (c + 1) * 64 + lr) * ZD + seg * 32);
            #pragma unroll
            for (int q = 0; q < 8; ++q) zreg[q] = zp[q];
        }
        __syncthreads();   // B: zn ready, copy-out reads of gl done

        // ---- MFMA: 4 m-tiles x 3 owned n-tiles x 4 k ----
        f32x4 acc0[4], acc1[4], acc2[4];
        #pragma unroll
        for (int m = 0; m < 4; ++m) {
            acc0[m] = (f32x4){0.f, 0.f, 0.f, 0.f};
            acc1[m] = (f32x4){0.f, 0.f, 0.f, 0.f};
            acc2[m] = (f32x4){0.f, 0.f, 0.f, 0.f};
        }
        #pragma unroll
        for (int m = 0; m < 4; ++m) {
            bf16x8 afm[4];
            #pragma unroll
            for (int kk = 0; kk < 4; ++kk)
                afm[kk] = *(const bf16x8*)&zn[m * 16 + fr][kk * 32 + hi * 8];
            #pragma unroll
            for (int kk = 0; kk < 4; ++kk) {
                acc0[m] = __builtin_amdgcn_mfma_f32_16x16x32_bf16(afm[kk], bv0[kk], acc0[m], 0, 0, 0);
                acc1[m] = __builtin_amdgcn_mfma_f32_16x16x32_bf16(afm[kk], bv1[kk], acc1[m], 0, 0, 0);
                acc2[m] = __builtin_amdgcn_mfma_f32_16x16x32_bf16(afm[kk], bv2[kk], acc2[m], 0, 0, 0);
            }
        }

        // ---- epilogue ----
        const size_t rb = blockrow + (size_t)c * 64;
        if (wave < 2) {
            // a = (a_lin + ab) * sigm(ag_lin + agb) -> a_t c-major
            const int ch = wave * 16 + fr;
            #pragma unroll
            for (int m = 0; m < 4; ++m) {
                union { ushort u[4]; uint2 d; } pk;
                #pragma unroll
                for (int q = 0; q < 4; ++q)
                    pk.u[q] = f2bf((acc0[m][q] + abv) * sigm(acc1[m][q] + agbv));
                *(uint2*)&a_t[(size_t)ch * LL + rb + m * 16 + hi * 4] = pk.d;
            }
            // gate tile t2 -> gl transpose
            const int gch = t2 * 16 - 64 + fr;
            #pragma unroll
            for (int m = 0; m < 4; ++m)
                #pragma unroll
                for (int q = 0; q < 4; ++q)
                    gl[m * 16 + hi * 4 + q][gch] = f2bf(sigm(acc2[m][q] + gbv2));
        } else {
            const int g0 = t0 * 16 - 64 + fr;
            const int g1 = t1 * 16 - 64 + fr;
            const int g2 = t2 * 16 - 64 + fr;
            #pragma unroll
            for (int m = 0; m < 4; ++m)
                #pragma unroll
                for (int q = 0; q < 4; ++q) {
                    const int row = m * 16 + hi * 4 + q;
                    gl[row][g0] = f2bf(sigm(acc0[m][q] + gbv0));
                    gl[row][g1] = f2bf(sigm(acc1[m][q] + gbv1));
                    gl[row][g2] = f2bf(sigm(acc2[m][q] + gbv2));
                }
        }
    }
    __syncthreads();       // chunk 3's gl complete
    copy_out(3);
}

// ---------------------------------------------------------------------------
// k2 v4 (R15/R16): 128x128 tile + bijective XCD swizzle (672 % 8 == 0).
// BK=32 double-buffered, global_load_lds, 4 waves 2x2, acc[4][4].
// ---------------------------------------------------------------------------
__global__ __launch_bounds__(256) void k2_einsum(
    const ushort* __restrict__ a_t, ushort* __restrict__ obuf16)
{
    __shared__ ushort As[2][128][32];
    __shared__ ushort Bs[2][128][32];

    const int tid = threadIdx.x;
    const int lid = blockIdx.y * 21 + blockIdx.x;     // dispatch-linear id
    const int swz = (lid & 7) * 84 + (lid >> 3);      // bijective XCD cluster
    const int c = swz / 21;
    int p = swz % 21, bi = 0;                         // 21 pairs over 6 tiles
    while (p >= 6 - bi) { p -= 6 - bi; ++bi; }
    const int bj = bi + p;
    const int i0 = bi * 128, j0 = bj * 128;
    const ushort* base = a_t + (size_t)c * LL;

    const int wave = tid >> 6, lane = tid & 63;
    const int wr = (wave >> 1) * 64, wc = (wave & 1) * 64;
    const int fr = lane & 15, hi = lane >> 4, k8 = hi * 8;

    f32x4 acc[4][4];
    #pragma unroll
    for (int m = 0; m < 4; ++m)
        #pragma unroll
        for (int n = 0; n < 4; ++n)
            acc[m][n] = (f32x4){0.f, 0.f, 0.f, 0.f};

    auto stage = [&](int b, int kc) {
        #pragma unroll
        for (int i = 0; i < 2; ++i) {
            const int idx = i * 256 + tid;       // 512 x 16B chunks
            const int row = idx >> 2, sc = (idx & 3) * 8;
            __builtin_amdgcn_global_load_lds(
                (const uint*)(base + (size_t)(i0 + row) * LDIM + kc * 32 + sc),
                (uint*)&As[b][row][sc], 16, 0, 0);
            __builtin_amdgcn_global_load_lds(
                (const uint*)(base + (size_t)(j0 + row) * LDIM + kc * 32 + sc),
                (uint*)&Bs[b][row][sc], 16, 0, 0);
        }
    };

    stage(0, 0);
    __syncthreads();
    for (int kc = 0; kc < 24; ++kc) {
        const int cur = kc & 1;
        if (kc + 1 < 24) stage(cur ^ 1, kc + 1);

        bf16x8 av[4], bv[4];
        #pragma unroll
        for (int m = 0; m < 4; ++m)
            av[m] = *(const bf16x8*)&As[cur][wr + m * 16 + fr][k8];
        #pragma unroll
        for (int n = 0; n < 4; ++n)
            bv[n] = *(const bf16x8*)&Bs[cur][wc + n * 16 + fr][k8];

        #pragma unroll
        for (int m = 0; m < 4; ++m)
            #pragma unroll
            for (int n = 0; n < 4; ++n)
                acc[m][n] = __builtin_amdgcn_mfma_f32_16x16x32_bf16(
                    av[m], bv[n], acc[m][n], 0, 0, 0);
        __syncthreads();
    }

    ushort* ob = obuf16 + (size_t)c * LL;
    #pragma unroll
    for (int m = 0; m < 4; ++m)
        #pragma unroll
        for (int n = 0; n < 4; ++n) {
            #pragma unroll
            for (int q = 0; q < 4; ++q) {
                const int row = i0 + wr + m * 16 + hi * 4 + q;
                const int col = j0 + wc + n * 16 + fr;
                ob[(size_t)row * LDIM + col] = f2bf(acc[m][n][q]);
            }
            if (bi != bj) {
                const int mrow = j0 + wc + n * 16 + fr;
                const int mcol = i0 + wr + m * 16 + hi * 4;
                union { ushort u[4]; uint2 d; } pk;
                #pragma unroll
                for (int q = 0; q < 4; ++q) pk.u[q] = f2bf(acc[m][n][q]);
                *(uint2*)&ob[(size_t)mrow * LDIM + mcol] = pk.d;
            }
        }
}

// ---------------------------------------------------------------------------
// k3 v7 (R16 measured-best): bf16 LDS, de-aliased, single cross-wave barrier.
//   LDS: Ol[64][40] + An[64][40] + Res[64][136], all ushort = 27.6 KB.
//   Everything after the gather-barrier is wave-private; lgkmcnt fences
//   guard same-wave LDS handoffs.  Big-stream patterns coalesced.
// ---------------------------------------------------------------------------
__global__ __launch_bounds__(256) void k3_out(
    const ushort* __restrict__ obuf16,
    const float* __restrict__ onw, const float* __restrict__ onb,
    const ushort* __restrict__ ofrag, const float* __restrict__ obias,
    const ushort* __restrict__ gate, float* __restrict__ out)
{
    __shared__ ushort Ol[64][40];
    __shared__ ushort An[64][40];
    __shared__ ushort Res[64][136];

    const int tid = threadIdx.x;
    const int lane = tid & 63, wave = tid >> 6;
    const int fr = lane & 15, hi = lane >> 4;
    const size_t rowbase = (size_t)blockIdx.x * 64;
    const int wrow = wave * 16;

    // ---- o_w frags: all 8 n-tiles in regs (coalesced 16B/lane, L2-hot) ----
    bf16x8 ofr[8];
    #pragma unroll
    for (int n = 0; n < 8; ++n)
        ofr[n] = *(const bf16x8*)&ofrag[(size_t)n * 512 + lane * 8];

    // ---- gather obuf16 (c-major bf16): wave handles 8 channels, 2 rows/uint ----
    #pragma unroll
    for (int cc = 0; cc < 4; ++cc) {
        const int ch = wave * 8 + cc * 2 + (lane >> 5);
        const int r2 = (lane & 31) * 2;
        const uint uu = *(const uint*)&obuf16[(size_t)ch * LL + rowbase + r2];
        Ol[r2][ch]     = (ushort)(uu & 0xffff);
        Ol[r2 + 1][ch] = (ushort)(uu >> 16);
    }
    __syncthreads();   // the ONLY cross-wave dependency

    // ---- LN over C=32 (wave-private rows): 4 lanes/row, 8 ch each ----
    {
        const int r = wrow + (lane >> 2), seg = lane & 3;
        union { uint4 q; ushort us[8]; } raw;
        raw.q = *(const uint4*)&Ol[r][seg * 8];
        float v[8];
        #pragma unroll
        for (int e = 0; e < 8; ++e) v[e] = bf2f(raw.us[e]);
        float s = 0.f, ss = 0.f;
        #pragma unroll
        for (int e = 0; e < 8; ++e) { s += v[e]; ss += v[e] * v[e]; }
        s += __shfl_xor(s, 1); ss += __shfl_xor(ss, 1);
        s += __shfl_xor(s, 2); ss += __shfl_xor(ss, 2);
        const float mu  = s * (1.f / 32.f);
        const float var = ss * (1.f / 32.f) - mu * mu;
        const float rs  = rsqrtf(var + 1e-5f);
        union { ushort us[8]; uint4 q; } pk;
        #pragma unroll
        for (int e = 0; e < 8; ++e) {
            const int c = seg * 8 + e;
            pk.us[e] = f2bf((v[e] - mu) * rs * onw[c] + onb[c]);
        }
        *(uint4*)&An[r][seg * 8] = pk.q;
    }
    asm volatile("s_waitcnt lgkmcnt(0)" ::: "memory");

    // ---- MFMA: wave w -> own rows wrow..+15, 128 outputs, single k-step ----
    const bf16x8 af = *(const bf16x8*)&An[wrow + fr][hi * 8];
    f32x4 acc[8];
    #pragma unroll
    for (int n = 0; n < 8; ++n)
        acc[n] = __builtin_amdgcn_mfma_f32_16x16x32_bf16(
            af, ofr[n], (f32x4){0.f, 0.f, 0.f, 0.f}, 0, 0, 0);

    // ---- +bias -> Res bf16 (own rows only) ----
    #pragma unroll
    for (int n = 0; n < 8; ++n) {
        const int ch = n * 16 + fr;
        const float obv = obias[ch];
        #pragma unroll
        for (int q = 0; q < 4; ++q)
            Res[wrow + hi * 4 + q][ch] = f2bf(acc[n][q] + obv);
    }
    asm volatile("s_waitcnt lgkmcnt(0)" ::: "memory");

    // ---- Res * gate -> out (wave-private rows, coalesced big streams) ----
    #pragma unroll
    for (int it = 0; it < 8; ++it) {
        const int r = wrow + it * 2 + (lane >> 5);     // 2 rows/iter
        const int ch = (lane & 31) * 4;
        union { uint2 d; ushort us[4]; } rv, g;
        rv.d = *(const uint2*)&Res[r][ch];
        g.d  = *(const uint2*)&gate[(rowbase + r) * ZD + ch];
        float4 w;
        w.x = bf2f(rv.us[0]) * bf2f(g.us[0]);
        w.y = bf2f(rv.us[1]) * bf2f(g.us[1]);
        w.z = bf2f(rv.us[2]) * bf2f(g.us[2]);
        w.w = bf2f(rv.us[3]) * bf2f(g.us[3]);
        *(float4*)&out[(rowbase + r) * ZD + ch] = w;
    }
}

extern "C" void kernel_launch(void* const* d_in, const int* in_sizes, int n_in,
                              void* d_out, int out_size, void* d_ws, size_t ws_size,
                              hipStream_t stream) {
    (void)in_sizes; (void)n_in; (void)out_size; (void)ws_size;
    const float* z   = (const float*)d_in[0];
    const float* nw  = (const float*)d_in[1];
    const float* nb  = (const float*)d_in[2];
    const float* onw = (const float*)d_in[3];
    const float* onb = (const float*)d_in[4];
    const float* aw  = (const float*)d_in[5];
    const float* ab  = (const float*)d_in[6];
    const float* agw = (const float*)d_in[7];
    const float* agb = (const float*)d_in[8];
    const float* gw  = (const float*)d_in[9];
    const float* gb  = (const float*)d_in[10];
    const float* ow  = (const float*)d_in[11];
    const float* ob  = (const float*)d_in[12];

    char* ws = (char*)d_ws;
    ushort* a_t    = (ushort*)ws;                       // 37,748,736 B
    ushort* gate   = (ushort*)(ws + 37748736);          // 150,994,944 B
    ushort* obuf16 = (ushort*)(ws + 188743680);         // 37,748,736 B
    ushort* wfrag  = (ushort*)(ws + 226492416);         // 49,152 B
    ushort* ofrag  = (ushort*)(ws + 226541568);         // 8,192 B

    k0_wfrag<<<14, 256, 0, stream>>>(aw, agw, gw, ow, wfrag, ofrag);
    k1_ln_proj<<<LL / 256, 256, 0, stream>>>(z, nw, nb, wfrag, ab, agb, gb,
                                             a_t, gate);
    k2_einsum<<<dim3(21, 32), 256, 0, stream>>>(a_t, obuf16);
    k3_out<<<LL / 64, 256, 0, stream>>>(obuf16, onw, onb, ofrag, ob, gate,
                                        (float*)d_out);
}